// Round 11
// baseline (811.279 us; speedup 1.0000x reference)
//
#include <hip/hip_runtime.h>

#define DD 96
#define HH 4
#define HD 384
#define NEG_SLOPE 0.2f
#define SCAN_BS 1024     // elements per scan block
#define WTC 400          // wt padded col count (384 W + 8 WA + 8 zero)

typedef unsigned int uint;
typedef unsigned short ushort;
typedef __attribute__((ext_vector_type(8))) short bf16x8;
typedef __attribute__((ext_vector_type(4))) float f32x4;

__device__ inline uint pack2bf(float lo, float hi) {   // round-to-nearest-even both halves
    uint ulo = __float_as_uint(lo); ulo += 0x7fffu + ((ulo >> 16) & 1u);
    uint uhi = __float_as_uint(hi); uhi += 0x7fffu + ((uhi >> 16) & 1u);
    return (ulo >> 16) | (uhi & 0xffff0000u);
}
__device__ inline ushort f2bf(float f) {
    uint u = __float_as_uint(f);
    u += 0x7fffu + ((u >> 16) & 1u);
    return (ushort)(u >> 16);
}

// ---------------- WA[l][k][j] = sum_c W[l][k][c] * A[c][j] ----------------
__global__ void wa_kernel(const float* __restrict__ W, const float* __restrict__ att_src,
                          const float* __restrict__ att_dst, float* __restrict__ wa) {
    const int l = blockIdx.x / DD;
    const int k = blockIdx.x % DD;
    const int t = threadIdx.x;          // 0..63
    const float* Wr = W + ((size_t)l * DD + k) * HD;
    const float* as = att_src + (size_t)l * HD;
    const float* ad = att_dst + (size_t)l * HD;
    const bool hiHalf = t >= 32;
    float s0=0,s1=0,s2=0,s3=0,d0=0,d1=0,d2=0,d3=0;
    int c; float w, ps, pd;
    c = t;       w = Wr[c]; s0 = fmaf(w, as[c], s0); d0 = fmaf(w, ad[c], d0);
    c = t + 64;  w = Wr[c]; ps = w * as[c]; pd = w * ad[c];
    s0 += hiHalf ? 0.f : ps;  s1 += hiHalf ? ps : 0.f;
    d0 += hiHalf ? 0.f : pd;  d1 += hiHalf ? pd : 0.f;
    c = t + 128; w = Wr[c]; s1 = fmaf(w, as[c], s1); d1 = fmaf(w, ad[c], d1);
    c = t + 192; w = Wr[c]; s2 = fmaf(w, as[c], s2); d2 = fmaf(w, ad[c], d2);
    c = t + 256; w = Wr[c]; ps = w * as[c]; pd = w * ad[c];
    s2 += hiHalf ? 0.f : ps;  s3 += hiHalf ? ps : 0.f;
    d2 += hiHalf ? 0.f : pd;  d3 += hiHalf ? pd : 0.f;
    c = t + 320; w = Wr[c]; s3 = fmaf(w, as[c], s3); d3 = fmaf(w, ad[c], d3);
#pragma unroll
    for (int off = 32; off; off >>= 1) {
        s0 += __shfl_xor(s0, off); s1 += __shfl_xor(s1, off);
        s2 += __shfl_xor(s2, off); s3 += __shfl_xor(s3, off);
        d0 += __shfl_xor(d0, off); d1 += __shfl_xor(d1, off);
        d2 += __shfl_xor(d2, off); d3 += __shfl_xor(d3, off);
    }
    if (t == 0) {
        float* o = wa + ((size_t)l * DD + k) * 8;
        o[0]=s0; o[1]=d0; o[2]=s1; o[3]=d1; o[4]=s2; o[5]=d2; o[6]=s3; o[7]=d3;
    }
}

// ---------------- wt[l][c][k] = bf16 of W^T (c<384), WA (384..391), 0 (392..399) -----
__global__ void wt_kernel(const float* __restrict__ W, const float* __restrict__ wa,
                          ushort* __restrict__ wt) {
    const int l = blockIdx.x / WTC;
    const int c = blockIdx.x % WTC;
    const int k = threadIdx.x;          // 0..95
    float v = 0.f;
    if (c < HD)        v = W[((size_t)l * DD + k) * HD + c];
    else if (c < HD+8) v = wa[((size_t)l * DD + k) * 8 + (c - HD)];
    wt[((size_t)l * WTC + c) * DD + k] = f2bf(v);
}

// ---------------- MFMA GEMM + fused alpha (+ optional fused BN of previous layer) ----
// Also zeroes bnsum[192] (block 0) so the following agg can accumulate BN stats.
template<int FUSE>
__global__ void __launch_bounds__(256) gemm_mfma_kernel(const float* __restrict__ xin,
        const float* __restrict__ scsh, const float* __restrict__ xres,
        float* __restrict__ xout, float* __restrict__ bnsum,
        const ushort* __restrict__ wt, uint* __restrict__ hp,
        float* __restrict__ asrc, float* __restrict__ adst, int N) {
    const int t = threadIdx.x;
    const int w = t >> 6;
    const int lane = t & 63;
    const int q = lane & 15, g = lane >> 4;
    const int base = blockIdx.x * 64 + w * 16;
    const int nA = min(base + q, N - 1);          // A-row node (clamped for tail)
    if (blockIdx.x == 0 && t < 192) bnsum[t] = 0.f;

    f32x4 acc[25];
#pragma unroll
    for (int i = 0; i < 25; i++) acc[i] = (f32x4){0.f, 0.f, 0.f, 0.f};

#pragma unroll
    for (int s = 0; s < 3; s++) {
        const int kbase = s * 32 + g * 8;
        float xv[8];
        if (FUSE == 0) {
            const float* xp = xin + (size_t)nA * DD + kbase;
            const float4 xa = *(const float4*)xp;
            const float4 xb = *(const float4*)(xp + 4);
            xv[0]=xa.x; xv[1]=xa.y; xv[2]=xa.z; xv[3]=xa.w;
            xv[4]=xb.x; xv[5]=xb.y; xv[6]=xb.z; xv[7]=xb.w;
        } else {
            const float* yp = xin + (size_t)nA * DD + kbase;
            const float* rp = xres + (size_t)nA * DD + kbase;
            const float4 ya = *(const float4*)yp;
            const float4 yb = *(const float4*)(yp + 4);
            const float4 ra = *(const float4*)rp;
            const float4 rb = *(const float4*)(rp + 4);
            const float yv[8] = {ya.x,ya.y,ya.z,ya.w,yb.x,yb.y,yb.z,yb.w};
            const float rv[8] = {ra.x,ra.y,ra.z,ra.w,rb.x,rb.y,rb.z,rb.w};
#pragma unroll
            for (int j = 0; j < 8; j++) {
                const int d = kbase + j;
                float a = fmaf(yv[j], scsh[d], scsh[d + DD]);
                xv[j] = (a > 0.f ? a : 0.f) + rv[j];
            }
            float* op = xout + (size_t)nA * DD + kbase;
            *(float4*)op       = make_float4(xv[0], xv[1], xv[2], xv[3]);
            *(float4*)(op + 4) = make_float4(xv[4], xv[5], xv[6], xv[7]);
        }
        union { uint u[4]; bf16x8 v; } A;
        A.u[0] = pack2bf(xv[0], xv[1]);
        A.u[1] = pack2bf(xv[2], xv[3]);
        A.u[2] = pack2bf(xv[4], xv[5]);
        A.u[3] = pack2bf(xv[6], xv[7]);
#pragma unroll
        for (int tt = 0; tt < 25; tt++) {
            const ushort* wp = wt + (size_t)(tt * 16 + q) * DD + kbase;
            union { uint4 u4; bf16x8 v; } B;
            B.u4 = *(const uint4*)wp;
            acc[tt] = __builtin_amdgcn_mfma_f32_16x16x32_bf16(A.v, B.v, acc[tt], 0, 0, 0);
        }
    }
#pragma unroll
    for (int r = 0; r < 4; r++) {
        const int node = base + g * 4 + r;
        if (node < N) {
            uint* hr = hp + (size_t)node * 192;
#pragma unroll
            for (int p = 0; p < 3; p++)
#pragma unroll
                for (int tt = 0; tt < 4; tt++)
                    hr[p * 64 + tt * 16 + q] = pack2bf(acc[p * 8 + tt][r], acc[p * 8 + tt + 4][r]);
            if (q < 8) {
                const float v = acc[24][r];
                if ((q & 1) == 0) asrc[node * 4 + (q >> 1)] = v;
                else              adst[node * 4 + (q >> 1)] = v;
            }
        }
    }
}

// ---------------- CSR build ----------------
__global__ void count_kernel(const int* __restrict__ ei, int* __restrict__ deg, int E) {
    int i = blockIdx.x * blockDim.x + threadIdx.x;
    const int stride = gridDim.x * blockDim.x;
    for (; i < E; i += stride) atomicAdd(&deg[ei[E + i]], 1);
}

__global__ void scan1_kernel(const int* __restrict__ deg, int* __restrict__ locpre,
                             int* __restrict__ bsum, int N) {
    __shared__ int ts[256];
    const int t = threadIdx.x;
    const int base = blockIdx.x * SCAN_BS + t * 4;
    int e0 = 0, e1 = 0, e2 = 0, e3 = 0;
    if (base + 3 < N) {
        const int4 v = *(const int4*)(deg + base);
        e0 = v.x + 1; e1 = v.y + 1; e2 = v.z + 1; e3 = v.w + 1;
    } else {
        if (base     < N) e0 = deg[base]     + 1;
        if (base + 1 < N) e1 = deg[base + 1] + 1;
        if (base + 2 < N) e2 = deg[base + 2] + 1;
        if (base + 3 < N) e3 = deg[base + 3] + 1;
    }
    const int s = e0 + e1 + e2 + e3;
    ts[t] = s;
    __syncthreads();
    for (int off = 1; off < 256; off <<= 1) {
        const int u = (t >= off) ? ts[t - off] : 0;
        __syncthreads();
        ts[t] += u;
        __syncthreads();
    }
    const int ex = ts[t] - s;
    if (base + 3 < N) {
        *(int4*)(locpre + base) = make_int4(ex, ex + e0, ex + e0 + e1, ex + e0 + e1 + e2);
    } else if (base < N) {
        locpre[base] = ex;
        if (base + 1 < N) locpre[base + 1] = ex + e0;
        if (base + 2 < N) locpre[base + 2] = ex + e0 + e1;
    }
    if (t == 255) bsum[blockIdx.x] = ts[255];
}

// phase 2+3 merged: each block redundantly scans the (<=64) block totals
__global__ void scan3_kernel(const int* __restrict__ locpre, const int* __restrict__ bsum,
                             int* __restrict__ rowptr, int* __restrict__ cursor,
                             int N, int NBLK) {
    __shared__ int s_boff, s_total;
    const int t = threadIdx.x;
    if (t < 64) {
        const int mine = (t < NBLK) ? bsum[t] : 0;
        int incl = mine;
#pragma unroll
        for (int off = 1; off < 64; off <<= 1) {
            const int u = __shfl_up(incl, off);
            if (t >= off) incl += u;
        }
        if (t == (int)blockIdx.x) s_boff = incl - mine;
        if (t == NBLK - 1) s_total = incl;
    }
    __syncthreads();
    const int boff = s_boff;
    const int base = blockIdx.x * SCAN_BS + t * 4;
    if (base + 3 < N) {
        int4 v = *(const int4*)(locpre + base);
        v.x += boff; v.y += boff; v.z += boff; v.w += boff;
        *(int4*)(rowptr + base) = v;
        *(int4*)(cursor + base) = v;
    } else {
        for (int i = base; i < N && i < base + 4; i++) {
            const int r = locpre[i] + boff;
            rowptr[i] = r; cursor[i] = r;
        }
    }
    if (blockIdx.x == 0 && t == 0) rowptr[N] = s_total;
}

__global__ void scatter_kernel(const int* __restrict__ ei, int* __restrict__ cursor,
                               const int* __restrict__ rowptr, int* __restrict__ col,
                               int E, int Etot) {
    int i = blockIdx.x * blockDim.x + threadIdx.x;
    const int stride = gridDim.x * blockDim.x;
    for (; i < Etot; i += stride) {
        if (i < E) {
            const int src = ei[i], dst = ei[E + i];
            col[atomicAdd(&cursor[dst], 1)] = src;
        } else {
            const int n = i - E;
            col[rowptr[n + 1] - 1] = n;     // self-loop slot, non-atomic
        }
    }
}

// ---------------- fused aggregate: inline edge weights + y + BN partial stats -------
#define EDGE_FMA(u0, u1, u2, w4)                                                      \
    { den0 += w4.x; den1 += w4.y; den2 += w4.z; den3 += w4.w;                         \
      const float cf1 = hi32 ? w4.y : w4.x;                                           \
      const float cf4 = hi32 ? w4.w : w4.z;                                           \
      acc0 = fmaf(__uint_as_float(u0 << 16), w4.x, acc0);                             \
      acc1 = fmaf(__uint_as_float(u0 & 0xffff0000u), cf1, acc1);                      \
      acc2 = fmaf(__uint_as_float(u1 << 16), w4.y, acc2);                             \
      acc3 = fmaf(__uint_as_float(u1 & 0xffff0000u), w4.z, acc3);                     \
      acc4 = fmaf(__uint_as_float(u2 << 16), cf4, acc4);                              \
      acc5 = fmaf(__uint_as_float(u2 & 0xffff0000u), w4.w, acc5); }

__global__ void __launch_bounds__(256) agg_csr_kernel(
        const int* __restrict__ rowptr, const int* __restrict__ col,
        const uint* __restrict__ hp, const float* __restrict__ asrc,
        const float* __restrict__ adst, const float* __restrict__ bias,
        float* __restrict__ y, float* __restrict__ bnsum, int N) {
    __shared__ float4 wls[4][64];
    __shared__ int    sls[4][64];
    __shared__ float  bsm[4][96];
    __shared__ float  bsq[4][96];
    const int t = threadIdx.x;
    const int lane = t & 63;
    const int wv = t >> 6;
    const bool hi32 = lane >= 32;
    const int n = (blockIdx.x * blockDim.x + t) >> 6;
    const bool valid = n < N;
    int beg = 0, endp = 0;
    float4 adv = make_float4(0.f, 0.f, 0.f, 0.f);
    if (valid) { beg = rowptr[n]; endp = rowptr[n + 1]; adv = ((const float4*)adst)[n]; }
    float acc0=0,acc1=0,acc2=0,acc3=0,acc4=0,acc5=0;
    float den0=0,den1=0,den2=0,den3=0;

    for (int cs = beg; cs < endp; cs += 64) {
        const int cnt = min(64, endp - cs);
        if (lane < cnt) {
            const int s = col[cs + lane];
            const float4 av = ((const float4*)asrc)[s];
            float e0 = av.x + adv.x, e1 = av.y + adv.y;
            float e2 = av.z + adv.z, e3 = av.w + adv.w;
            e0 = e0 > 0.f ? e0 : NEG_SLOPE * e0;
            e1 = e1 > 0.f ? e1 : NEG_SLOPE * e1;
            e2 = e2 > 0.f ? e2 : NEG_SLOPE * e2;
            e3 = e3 > 0.f ? e3 : NEG_SLOPE * e3;
            sls[wv][lane] = s;
            wls[wv][lane] = make_float4(__expf(e0), __expf(e1), __expf(e2), __expf(e3));
        }
        __builtin_amdgcn_wave_barrier();    // wave-local LDS: per-wave DS pipe is in-order
        int j = 0;
        for (; j + 4 <= cnt; j += 4) {
            const int4 sv = *(const int4*)&sls[wv][j];
            const float4 wA = wls[wv][j],     wB = wls[wv][j + 1];
            const float4 wC = wls[wv][j + 2], wD = wls[wv][j + 3];
            const uint* h0 = hp + (size_t)sv.x * 192 + lane;
            const uint* h1 = hp + (size_t)sv.y * 192 + lane;
            const uint* h2 = hp + (size_t)sv.z * 192 + lane;
            const uint* h3 = hp + (size_t)sv.w * 192 + lane;
            const uint u00 = h0[0], u01 = h0[64], u02 = h0[128];
            const uint u10 = h1[0], u11 = h1[64], u12 = h1[128];
            const uint u20 = h2[0], u21 = h2[64], u22 = h2[128];
            const uint u30 = h3[0], u31 = h3[64], u32 = h3[128];
            EDGE_FMA(u00, u01, u02, wA);
            EDGE_FMA(u10, u11, u12, wB);
            EDGE_FMA(u20, u21, u22, wC);
            EDGE_FMA(u30, u31, u32, wD);
        }
        for (; j < cnt; j++) {
            const int s0 = sls[wv][j];
            const float4 wA = wls[wv][j];
            const uint* h0 = hp + (size_t)s0 * 192 + lane;
            const uint u00 = h0[0], u01 = h0[64], u02 = h0[128];
            EDGE_FMA(u00, u01, u02, wA);
        }
        __builtin_amdgcn_wave_barrier();
    }
    const float r0 = 0.25f / (den0 + 1e-16f);
    const float r1 = 0.25f / (den1 + 1e-16f);
    const float r2 = 0.25f / (den2 + 1e-16f);
    const float r3 = 0.25f / (den3 + 1e-16f);
    const float rc1 = hi32 ? r1 : r0;
    const float rc4 = hi32 ? r3 : r2;
    const float A = acc0 * r0 + acc3 * r2;
    const float B = acc1 * rc1 + acc4 * rc4;
    const float C = acc2 * r1 + acc5 * r3;
    const float shB = __shfl_xor(B, 32);
    const float shC = __shfl_xor(C, 32);
    float val0 = 0.f, val1 = 0.f;
    if (valid) {
        val0 = A + (hi32 ? shC : shB) + bias[lane];
        val1 = B + shC + bias[64 + lane];            // meaningful for lane<32
        float* yr = y + (size_t)n * DD;
        yr[lane] = val0;
        if (!hi32) yr[64 + lane] = val1;
    }
    // per-block BN partials: features 0..63 from val0 (all lanes), 64..95 from val1
    bsm[wv][lane] = val0;
    bsq[wv][lane] = val0 * val0;
    if (!hi32) {
        const float v1 = valid ? val1 : 0.f;
        bsm[wv][64 + lane] = v1;
        bsq[wv][64 + lane] = v1 * v1;
    }
    __syncthreads();
    if (t < 96) {
        const float s = bsm[0][t] + bsm[1][t] + bsm[2][t] + bsm[3][t];
        unsafeAtomicAdd(&bnsum[t], s);
    } else if (t < 192) {
        const int d = t - 96;
        const float q = bsq[0][d] + bsq[1][d] + bsq[2][d] + bsq[3][d];
        unsafeAtomicAdd(&bnsum[96 + d], q);
    }
}

// ---------------- BN finalize: scale/shift per feature ----------------
__global__ void bnfin_kernel(const float* __restrict__ bnsum, const float* __restrict__ gamma,
                             const float* __restrict__ beta, float* __restrict__ scsh, int N) {
    const int d = threadIdx.x;   // 96
    const float invN = 1.f / (float)N;
    const float mu = bnsum[d] * invN;
    const float var = bnsum[96 + d] * invN - mu * mu;
    const float sc = gamma[d] * rsqrtf(var + 1e-5f);
    scsh[d] = sc;
    scsh[d + DD] = beta[d] - mu * sc;
}

__global__ void bn_apply_kernel(const float* __restrict__ y, const float* __restrict__ scsh,
                                const float* __restrict__ xin, float* __restrict__ xout,
                                int total4) {
    int i = blockIdx.x * blockDim.x + threadIdx.x;
    const int stride = gridDim.x * blockDim.x;
    for (; i < total4; i += stride) {
        const int d4 = (i % 24) * 4;
        const float4 v = ((const float4*)y)[i];
        const float4 xi = ((const float4*)xin)[i];
        float4 o; float a;
        a = fmaf(v.x, scsh[d4],     scsh[d4 + DD]);     o.x = (a > 0.f ? a : 0.f) + xi.x;
        a = fmaf(v.y, scsh[d4 + 1], scsh[d4 + 1 + DD]); o.y = (a > 0.f ? a : 0.f) + xi.y;
        a = fmaf(v.z, scsh[d4 + 2], scsh[d4 + 2 + DD]); o.z = (a > 0.f ? a : 0.f) + xi.z;
        a = fmaf(v.w, scsh[d4 + 3], scsh[d4 + 3 + DD]); o.w = (a > 0.f ? a : 0.f) + xi.w;
        ((float4*)xout)[i] = o;
    }
}

extern "C" void kernel_launch(void* const* d_in, const int* in_sizes, int n_in,
                              void* d_out, int out_size, void* d_ws, size_t ws_size,
                              hipStream_t stream) {
    const float* x        = (const float*)d_in[0];
    const int*   ei       = (const int*)d_in[1];
    const float* W        = (const float*)d_in[2];
    const float* att_src  = (const float*)d_in[3];
    const float* att_dst  = (const float*)d_in[4];
    const float* bias     = (const float*)d_in[5];
    const float* gamma    = (const float*)d_in[6];
    const float* beta     = (const float*)d_in[7];
    float* out_final = (float*)d_out;

    const int N = in_sizes[0] / DD;     // 50000
    const int E = in_sizes[1] / 2;      // 800000
    const int Etot = E + N;
    const int NBLK = (N + SCAN_BS - 1) / SCAN_BS;   // 49 (must be <= 64)

    char* ws = (char*)d_ws;
    size_t off = 0;
    auto alloc = [&](size_t bytes) -> void* {
        void* p = ws + off;
        off += (bytes + 255) & ~(size_t)255;
        return p;
    };
    uint*   hp     = (uint*)alloc((size_t)N * 192 * 4);
    float*  asrc   = (float*)alloc((size_t)N * HH * 4);
    float*  adst   = (float*)alloc((size_t)N * HH * 4);
    float*  y      = (float*)alloc((size_t)N * DD * 4);
    float*  xbuf   = (float*)alloc((size_t)N * DD * 4);
    float*  bnsum  = (float*)alloc(192 * 4);
    float*  scsh   = (float*)alloc(2 * DD * 4);
    float*  wa     = (float*)alloc(2 * DD * 8 * 4);
    ushort* wt     = (ushort*)alloc((size_t)2 * WTC * DD * 2);
    int*    deg    = (int*)alloc((size_t)N * 4);
    int*    locpre = (int*)alloc((size_t)N * 4);
    int*    bsumi  = (int*)alloc(64 * 4);
    int*    rowptr = (int*)alloc((size_t)(N + 1) * 4);
    int*    cursor = (int*)alloc((size_t)N * 4);
    int*    colidx = (int*)alloc((size_t)Etot * 4);

    // ---- CSR by destination + WA/Wt precompute (layer-invariant structure) ----
    hipMemsetAsync(deg, 0, (size_t)N * 4, stream);
    count_kernel<<<1024, 256, 0, stream>>>(ei, deg, E);
    scan1_kernel<<<NBLK, 256, 0, stream>>>(deg, locpre, bsumi, N);
    scan3_kernel<<<NBLK, 256, 0, stream>>>(locpre, bsumi, rowptr, cursor, N, NBLK);
    scatter_kernel<<<1024, 256, 0, stream>>>(ei, cursor, rowptr, colidx, E, Etot);
    wa_kernel<<<2 * DD, 64, 0, stream>>>(W, att_src, att_dst, wa);
    wt_kernel<<<2 * WTC, DD, 0, stream>>>(W, wa, wt);

    // ---- layer 1 ----
    gemm_mfma_kernel<0><<<(N + 63) / 64, 256, 0, stream>>>(
        x, nullptr, nullptr, nullptr, bnsum, wt, hp, asrc, adst, N);
    agg_csr_kernel<<<(N * 64 + 255) / 256, 256, 0, stream>>>(
        rowptr, colidx, hp, asrc, adst, bias, y, bnsum, N);
    bnfin_kernel<<<1, DD, 0, stream>>>(bnsum, gamma, beta, scsh, N);

    // ---- layer 2 (layer-1 BN+ReLU+residual fused into gemm A-path; x1 -> xbuf) ----
    gemm_mfma_kernel<1><<<(N + 63) / 64, 256, 0, stream>>>(
        y, scsh, x, xbuf, bnsum, wt + (size_t)WTC * DD, hp, asrc, adst, N);
    agg_csr_kernel<<<(N * 64 + 255) / 256, 256, 0, stream>>>(
        rowptr, colidx, hp, asrc, adst, bias + DD, y, bnsum, N);
    bnfin_kernel<<<1, DD, 0, stream>>>(bnsum, gamma + DD, beta + DD, scsh, N);
    bn_apply_kernel<<<2048, 256, 0, stream>>>(y, scsh, xbuf, out_final, N * DD / 4);
}

// Round 12
// 428.370 us; speedup vs baseline: 1.8939x; 1.8939x over previous
//
#include <hip/hip_runtime.h>

#define DD 96
#define HH 4
#define HD 384
#define NEG_SLOPE 0.2f
#define SCAN_BS 1024     // elements per scan block
#define WTC 400          // wt padded col count (384 W + 8 WA + 8 zero)

typedef unsigned int uint;
typedef unsigned short ushort;
typedef __attribute__((ext_vector_type(8))) short bf16x8;
typedef __attribute__((ext_vector_type(4))) float f32x4;

__device__ inline uint pack2bf(float lo, float hi) {   // round-to-nearest-even both halves
    uint ulo = __float_as_uint(lo); ulo += 0x7fffu + ((ulo >> 16) & 1u);
    uint uhi = __float_as_uint(hi); uhi += 0x7fffu + ((uhi >> 16) & 1u);
    return (ulo >> 16) | (uhi & 0xffff0000u);
}
__device__ inline ushort f2bf(float f) {
    uint u = __float_as_uint(f);
    u += 0x7fffu + ((u >> 16) & 1u);
    return (ushort)(u >> 16);
}

// ---------------- WA[l][k][j] = sum_c W[l][k][c] * A[c][j] ----------------
__global__ void wa_kernel(const float* __restrict__ W, const float* __restrict__ att_src,
                          const float* __restrict__ att_dst, float* __restrict__ wa) {
    const int l = blockIdx.x / DD;
    const int k = blockIdx.x % DD;
    const int t = threadIdx.x;          // 0..63
    const float* Wr = W + ((size_t)l * DD + k) * HD;
    const float* as = att_src + (size_t)l * HD;
    const float* ad = att_dst + (size_t)l * HD;
    const bool hiHalf = t >= 32;
    float s0=0,s1=0,s2=0,s3=0,d0=0,d1=0,d2=0,d3=0;
    int c; float w, ps, pd;
    c = t;       w = Wr[c]; s0 = fmaf(w, as[c], s0); d0 = fmaf(w, ad[c], d0);
    c = t + 64;  w = Wr[c]; ps = w * as[c]; pd = w * ad[c];
    s0 += hiHalf ? 0.f : ps;  s1 += hiHalf ? ps : 0.f;
    d0 += hiHalf ? 0.f : pd;  d1 += hiHalf ? pd : 0.f;
    c = t + 128; w = Wr[c]; s1 = fmaf(w, as[c], s1); d1 = fmaf(w, ad[c], d1);
    c = t + 192; w = Wr[c]; s2 = fmaf(w, as[c], s2); d2 = fmaf(w, ad[c], d2);
    c = t + 256; w = Wr[c]; ps = w * as[c]; pd = w * ad[c];
    s2 += hiHalf ? 0.f : ps;  s3 += hiHalf ? ps : 0.f;
    d2 += hiHalf ? 0.f : pd;  d3 += hiHalf ? pd : 0.f;
    c = t + 320; w = Wr[c]; s3 = fmaf(w, as[c], s3); d3 = fmaf(w, ad[c], d3);
#pragma unroll
    for (int off = 32; off; off >>= 1) {
        s0 += __shfl_xor(s0, off); s1 += __shfl_xor(s1, off);
        s2 += __shfl_xor(s2, off); s3 += __shfl_xor(s3, off);
        d0 += __shfl_xor(d0, off); d1 += __shfl_xor(d1, off);
        d2 += __shfl_xor(d2, off); d3 += __shfl_xor(d3, off);
    }
    if (t == 0) {
        float* o = wa + ((size_t)l * DD + k) * 8;
        o[0]=s0; o[1]=d0; o[2]=s1; o[3]=d1; o[4]=s2; o[5]=d2; o[6]=s3; o[7]=d3;
    }
}

// ---------------- wt[l][c][k] = bf16 of W^T (c<384), WA (384..391), 0 (392..399) -----
__global__ void wt_kernel(const float* __restrict__ W, const float* __restrict__ wa,
                          ushort* __restrict__ wt) {
    const int l = blockIdx.x / WTC;
    const int c = blockIdx.x % WTC;
    const int k = threadIdx.x;          // 0..95
    float v = 0.f;
    if (c < HD)        v = W[((size_t)l * DD + k) * HD + c];
    else if (c < HD+8) v = wa[((size_t)l * DD + k) * 8 + (c - HD)];
    wt[((size_t)l * WTC + c) * DD + k] = f2bf(v);
}

// ---------------- MFMA GEMM + fused alpha (+ optional fused BN of previous layer) ----
template<int FUSE>
__global__ void __launch_bounds__(256) gemm_mfma_kernel(const float* __restrict__ xin,
        const float* __restrict__ scsh, const float* __restrict__ xres,
        float* __restrict__ xout,
        const ushort* __restrict__ wt, uint* __restrict__ hp,
        float* __restrict__ asrc, float* __restrict__ adst, int N) {
    const int t = threadIdx.x;
    const int w = t >> 6;
    const int lane = t & 63;
    const int q = lane & 15, g = lane >> 4;
    const int base = blockIdx.x * 64 + w * 16;
    const int nA = min(base + q, N - 1);          // A-row node (clamped for tail)

    f32x4 acc[25];
#pragma unroll
    for (int i = 0; i < 25; i++) acc[i] = (f32x4){0.f, 0.f, 0.f, 0.f};

#pragma unroll
    for (int s = 0; s < 3; s++) {
        const int kbase = s * 32 + g * 8;
        float xv[8];
        if (FUSE == 0) {
            const float* xp = xin + (size_t)nA * DD + kbase;
            const float4 xa = *(const float4*)xp;
            const float4 xb = *(const float4*)(xp + 4);
            xv[0]=xa.x; xv[1]=xa.y; xv[2]=xa.z; xv[3]=xa.w;
            xv[4]=xb.x; xv[5]=xb.y; xv[6]=xb.z; xv[7]=xb.w;
        } else {
            const float* yp = xin + (size_t)nA * DD + kbase;
            const float* rp = xres + (size_t)nA * DD + kbase;
            const float4 ya = *(const float4*)yp;
            const float4 yb = *(const float4*)(yp + 4);
            const float4 ra = *(const float4*)rp;
            const float4 rb = *(const float4*)(rp + 4);
            const float yv[8] = {ya.x,ya.y,ya.z,ya.w,yb.x,yb.y,yb.z,yb.w};
            const float rv[8] = {ra.x,ra.y,ra.z,ra.w,rb.x,rb.y,rb.z,rb.w};
#pragma unroll
            for (int j = 0; j < 8; j++) {
                const int d = kbase + j;
                float a = fmaf(yv[j], scsh[d], scsh[d + DD]);
                xv[j] = (a > 0.f ? a : 0.f) + rv[j];
            }
            float* op = xout + (size_t)nA * DD + kbase;
            *(float4*)op       = make_float4(xv[0], xv[1], xv[2], xv[3]);
            *(float4*)(op + 4) = make_float4(xv[4], xv[5], xv[6], xv[7]);
        }
        union { uint u[4]; bf16x8 v; } A;
        A.u[0] = pack2bf(xv[0], xv[1]);
        A.u[1] = pack2bf(xv[2], xv[3]);
        A.u[2] = pack2bf(xv[4], xv[5]);
        A.u[3] = pack2bf(xv[6], xv[7]);
#pragma unroll
        for (int tt = 0; tt < 25; tt++) {
            const ushort* wp = wt + (size_t)(tt * 16 + q) * DD + kbase;
            union { uint4 u4; bf16x8 v; } B;
            B.u4 = *(const uint4*)wp;
            acc[tt] = __builtin_amdgcn_mfma_f32_16x16x32_bf16(A.v, B.v, acc[tt], 0, 0, 0);
        }
    }
#pragma unroll
    for (int r = 0; r < 4; r++) {
        const int node = base + g * 4 + r;
        if (node < N) {
            uint* hr = hp + (size_t)node * 192;
#pragma unroll
            for (int p = 0; p < 3; p++)
#pragma unroll
                for (int tt = 0; tt < 4; tt++)
                    hr[p * 64 + tt * 16 + q] = pack2bf(acc[p * 8 + tt][r], acc[p * 8 + tt + 4][r]);
            if (q < 8) {
                const float v = acc[24][r];
                if ((q & 1) == 0) asrc[node * 4 + (q >> 1)] = v;
                else              adst[node * 4 + (q >> 1)] = v;
            }
        }
    }
}

// ---------------- CSR build ----------------
__global__ void count_kernel(const int* __restrict__ ei, int* __restrict__ deg, int E) {
    int i = blockIdx.x * blockDim.x + threadIdx.x;
    const int stride = gridDim.x * blockDim.x;
    for (; i < E; i += stride) atomicAdd(&deg[ei[E + i]], 1);
}

__global__ void scan1_kernel(const int* __restrict__ deg, int* __restrict__ locpre,
                             int* __restrict__ bsum, int N) {
    __shared__ int ts[256];
    const int t = threadIdx.x;
    const int base = blockIdx.x * SCAN_BS + t * 4;
    int e0 = 0, e1 = 0, e2 = 0, e3 = 0;
    if (base + 3 < N) {
        const int4 v = *(const int4*)(deg + base);
        e0 = v.x + 1; e1 = v.y + 1; e2 = v.z + 1; e3 = v.w + 1;
    } else {
        if (base     < N) e0 = deg[base]     + 1;
        if (base + 1 < N) e1 = deg[base + 1] + 1;
        if (base + 2 < N) e2 = deg[base + 2] + 1;
        if (base + 3 < N) e3 = deg[base + 3] + 1;
    }
    const int s = e0 + e1 + e2 + e3;
    ts[t] = s;
    __syncthreads();
    for (int off = 1; off < 256; off <<= 1) {
        const int u = (t >= off) ? ts[t - off] : 0;
        __syncthreads();
        ts[t] += u;
        __syncthreads();
    }
    const int ex = ts[t] - s;
    if (base + 3 < N) {
        *(int4*)(locpre + base) = make_int4(ex, ex + e0, ex + e0 + e1, ex + e0 + e1 + e2);
    } else if (base < N) {
        locpre[base] = ex;
        if (base + 1 < N) locpre[base + 1] = ex + e0;
        if (base + 2 < N) locpre[base + 2] = ex + e0 + e1;
    }
    if (t == 255) bsum[blockIdx.x] = ts[255];
}

// phase 2+3 merged: each block redundantly scans the (<=64) block totals
__global__ void scan3_kernel(const int* __restrict__ locpre, const int* __restrict__ bsum,
                             int* __restrict__ rowptr, int* __restrict__ cursor,
                             int N, int NBLK) {
    __shared__ int s_boff, s_total;
    const int t = threadIdx.x;
    if (t < 64) {
        const int mine = (t < NBLK) ? bsum[t] : 0;
        int incl = mine;
#pragma unroll
        for (int off = 1; off < 64; off <<= 1) {
            const int u = __shfl_up(incl, off);
            if (t >= off) incl += u;
        }
        if (t == (int)blockIdx.x) s_boff = incl - mine;
        if (t == NBLK - 1) s_total = incl;
    }
    __syncthreads();
    const int boff = s_boff;
    const int base = blockIdx.x * SCAN_BS + t * 4;
    if (base + 3 < N) {
        int4 v = *(const int4*)(locpre + base);
        v.x += boff; v.y += boff; v.z += boff; v.w += boff;
        *(int4*)(rowptr + base) = v;
        *(int4*)(cursor + base) = v;
    } else {
        for (int i = base; i < N && i < base + 4; i++) {
            const int r = locpre[i] + boff;
            rowptr[i] = r; cursor[i] = r;
        }
    }
    if (blockIdx.x == 0 && t == 0) rowptr[N] = s_total;
}

__global__ void scatter_kernel(const int* __restrict__ ei, int* __restrict__ cursor,
                               const int* __restrict__ rowptr, int* __restrict__ col,
                               int E, int Etot) {
    int i = blockIdx.x * blockDim.x + threadIdx.x;
    const int stride = gridDim.x * blockDim.x;
    for (; i < Etot; i += stride) {
        if (i < E) {
            const int src = ei[i], dst = ei[E + i];
            col[atomicAdd(&cursor[dst], 1)] = src;
        } else {
            const int n = i - E;
            col[rowptr[n + 1] - 1] = n;     // self-loop slot, non-atomic
        }
    }
}

// ---------------- fused aggregate: inline edge weights + y + BN block partials ------
#define EDGE_FMA(u0, u1, u2, w4)                                                      \
    { den0 += w4.x; den1 += w4.y; den2 += w4.z; den3 += w4.w;                         \
      const float cf1 = hi32 ? w4.y : w4.x;                                           \
      const float cf4 = hi32 ? w4.w : w4.z;                                           \
      acc0 = fmaf(__uint_as_float(u0 << 16), w4.x, acc0);                             \
      acc1 = fmaf(__uint_as_float(u0 & 0xffff0000u), cf1, acc1);                      \
      acc2 = fmaf(__uint_as_float(u1 << 16), w4.y, acc2);                             \
      acc3 = fmaf(__uint_as_float(u1 & 0xffff0000u), w4.z, acc3);                     \
      acc4 = fmaf(__uint_as_float(u2 << 16), cf4, acc4);                              \
      acc5 = fmaf(__uint_as_float(u2 & 0xffff0000u), w4.w, acc5); }

__global__ void __launch_bounds__(256) agg_csr_kernel(
        const int* __restrict__ rowptr, const int* __restrict__ col,
        const uint* __restrict__ hp, const float* __restrict__ asrc,
        const float* __restrict__ adst, const float* __restrict__ bias,
        float* __restrict__ y, float* __restrict__ pbuf, int N) {
    __shared__ float4 wls[4][64];
    __shared__ int    sls[4][64];
    __shared__ float  bsm[4][96];
    __shared__ float  bsq[4][96];
    const int t = threadIdx.x;
    const int lane = t & 63;
    const int wv = t >> 6;
    const bool hi32 = lane >= 32;
    const int n = (blockIdx.x * blockDim.x + t) >> 6;
    const bool valid = n < N;
    int beg = 0, endp = 0;
    float4 adv = make_float4(0.f, 0.f, 0.f, 0.f);
    if (valid) { beg = rowptr[n]; endp = rowptr[n + 1]; adv = ((const float4*)adst)[n]; }
    float acc0=0,acc1=0,acc2=0,acc3=0,acc4=0,acc5=0;
    float den0=0,den1=0,den2=0,den3=0;

    for (int cs = beg; cs < endp; cs += 64) {
        const int cnt = min(64, endp - cs);
        if (lane < cnt) {
            const int s = col[cs + lane];
            const float4 av = ((const float4*)asrc)[s];
            float e0 = av.x + adv.x, e1 = av.y + adv.y;
            float e2 = av.z + adv.z, e3 = av.w + adv.w;
            e0 = e0 > 0.f ? e0 : NEG_SLOPE * e0;
            e1 = e1 > 0.f ? e1 : NEG_SLOPE * e1;
            e2 = e2 > 0.f ? e2 : NEG_SLOPE * e2;
            e3 = e3 > 0.f ? e3 : NEG_SLOPE * e3;
            sls[wv][lane] = s;
            wls[wv][lane] = make_float4(__expf(e0), __expf(e1), __expf(e2), __expf(e3));
        }
        __builtin_amdgcn_wave_barrier();    // wave-local LDS: per-wave DS pipe is in-order
        int j = 0;
        for (; j + 4 <= cnt; j += 4) {
            const int4 sv = *(const int4*)&sls[wv][j];
            const float4 wA = wls[wv][j],     wB = wls[wv][j + 1];
            const float4 wC = wls[wv][j + 2], wD = wls[wv][j + 3];
            const uint* h0 = hp + (size_t)sv.x * 192 + lane;
            const uint* h1 = hp + (size_t)sv.y * 192 + lane;
            const uint* h2 = hp + (size_t)sv.z * 192 + lane;
            const uint* h3 = hp + (size_t)sv.w * 192 + lane;
            const uint u00 = h0[0], u01 = h0[64], u02 = h0[128];
            const uint u10 = h1[0], u11 = h1[64], u12 = h1[128];
            const uint u20 = h2[0], u21 = h2[64], u22 = h2[128];
            const uint u30 = h3[0], u31 = h3[64], u32 = h3[128];
            EDGE_FMA(u00, u01, u02, wA);
            EDGE_FMA(u10, u11, u12, wB);
            EDGE_FMA(u20, u21, u22, wC);
            EDGE_FMA(u30, u31, u32, wD);
        }
        for (; j < cnt; j++) {
            const int s0 = sls[wv][j];
            const float4 wA = wls[wv][j];
            const uint* h0 = hp + (size_t)s0 * 192 + lane;
            const uint u00 = h0[0], u01 = h0[64], u02 = h0[128];
            EDGE_FMA(u00, u01, u02, wA);
        }
        __builtin_amdgcn_wave_barrier();
    }
    const float r0 = 0.25f / (den0 + 1e-16f);
    const float r1 = 0.25f / (den1 + 1e-16f);
    const float r2 = 0.25f / (den2 + 1e-16f);
    const float r3 = 0.25f / (den3 + 1e-16f);
    const float rc1 = hi32 ? r1 : r0;
    const float rc4 = hi32 ? r3 : r2;
    const float A = acc0 * r0 + acc3 * r2;
    const float B = acc1 * rc1 + acc4 * rc4;
    const float C = acc2 * r1 + acc5 * r3;
    const float shB = __shfl_xor(B, 32);
    const float shC = __shfl_xor(C, 32);
    float val0 = 0.f, val1 = 0.f;
    if (valid) {
        val0 = A + (hi32 ? shC : shB) + bias[lane];
        val1 = B + shC + bias[64 + lane];            // meaningful for lane<32
        float* yr = y + (size_t)n * DD;
        yr[lane] = val0;
        if (!hi32) yr[64 + lane] = val1;
    }
    // per-block BN partials: features 0..63 from val0 (all lanes), 64..95 from val1
    bsm[wv][lane] = val0;
    bsq[wv][lane] = val0 * val0;
    if (!hi32) {
        const float v1 = valid ? val1 : 0.f;
        bsm[wv][64 + lane] = v1;
        bsq[wv][64 + lane] = v1 * v1;
    }
    __syncthreads();
    if (t < 96) {
        pbuf[(size_t)blockIdx.x * 192 + t] =
            bsm[0][t] + bsm[1][t] + bsm[2][t] + bsm[3][t];
    } else if (t < 192) {
        const int d = t - 96;
        pbuf[(size_t)blockIdx.x * 192 + t] =
            bsq[0][d] + bsq[1][d] + bsq[2][d] + bsq[3][d];
    }
}

// ---------------- BN reduce + finalize: block d sums partials, emits scsh ----------
__global__ void __launch_bounds__(256) bnred_kernel(const float* __restrict__ pbuf,
        const float* __restrict__ gamma, const float* __restrict__ beta,
        float* __restrict__ scsh, int NB, int N) {
    __shared__ float rs[256], rq[256];
    const int d = blockIdx.x;           // 0..95
    const int t = threadIdx.x;
    float s = 0.f, q = 0.f;
    for (int b = t; b < NB; b += 256) {
        s += pbuf[(size_t)b * 192 + d];
        q += pbuf[(size_t)b * 192 + 96 + d];
    }
    rs[t] = s; rq[t] = q;
    __syncthreads();
    for (int off = 128; off >= 1; off >>= 1) {
        if (t < off) { rs[t] += rs[t + off]; rq[t] += rq[t + off]; }
        __syncthreads();
    }
    if (t == 0) {
        const float invN = 1.f / (float)N;
        const float mu = rs[0] * invN;
        const float var = rq[0] * invN - mu * mu;
        const float sc = gamma[d] * rsqrtf(var + 1e-5f);
        scsh[d] = sc;
        scsh[d + DD] = beta[d] - mu * sc;
    }
}

__global__ void bn_apply_kernel(const float* __restrict__ y, const float* __restrict__ scsh,
                                const float* __restrict__ xin, float* __restrict__ xout,
                                int total4) {
    int i = blockIdx.x * blockDim.x + threadIdx.x;
    const int stride = gridDim.x * blockDim.x;
    for (; i < total4; i += stride) {
        const int d4 = (i % 24) * 4;
        const float4 v = ((const float4*)y)[i];
        const float4 xi = ((const float4*)xin)[i];
        float4 o; float a;
        a = fmaf(v.x, scsh[d4],     scsh[d4 + DD]);     o.x = (a > 0.f ? a : 0.f) + xi.x;
        a = fmaf(v.y, scsh[d4 + 1], scsh[d4 + 1 + DD]); o.y = (a > 0.f ? a : 0.f) + xi.y;
        a = fmaf(v.z, scsh[d4 + 2], scsh[d4 + 2 + DD]); o.z = (a > 0.f ? a : 0.f) + xi.z;
        a = fmaf(v.w, scsh[d4 + 3], scsh[d4 + 3 + DD]); o.w = (a > 0.f ? a : 0.f) + xi.w;
        ((float4*)xout)[i] = o;
    }
}

extern "C" void kernel_launch(void* const* d_in, const int* in_sizes, int n_in,
                              void* d_out, int out_size, void* d_ws, size_t ws_size,
                              hipStream_t stream) {
    const float* x        = (const float*)d_in[0];
    const int*   ei       = (const int*)d_in[1];
    const float* W        = (const float*)d_in[2];
    const float* att_src  = (const float*)d_in[3];
    const float* att_dst  = (const float*)d_in[4];
    const float* bias     = (const float*)d_in[5];
    const float* gamma    = (const float*)d_in[6];
    const float* beta     = (const float*)d_in[7];
    float* out_final = (float*)d_out;

    const int N = in_sizes[0] / DD;     // 50000
    const int E = in_sizes[1] / 2;      // 800000
    const int Etot = E + N;
    const int NBLK = (N + SCAN_BS - 1) / SCAN_BS;   // 49 (must be <= 64)
    const int NBAGG = (N * 64 + 255) / 256;         // agg blocks (4 nodes each)

    char* ws = (char*)d_ws;
    size_t off = 0;
    auto alloc = [&](size_t bytes) -> void* {
        void* p = ws + off;
        off += (bytes + 255) & ~(size_t)255;
        return p;
    };
    uint*   hp     = (uint*)alloc((size_t)N * 192 * 4);
    float*  asrc   = (float*)alloc((size_t)N * HH * 4);
    float*  adst   = (float*)alloc((size_t)N * HH * 4);
    float*  y      = (float*)alloc((size_t)N * DD * 4);
    float*  xbuf   = (float*)alloc((size_t)N * DD * 4);
    float*  pbuf   = (float*)alloc((size_t)NBAGG * 192 * 4);
    float*  scsh   = (float*)alloc(2 * DD * 4);
    float*  wa     = (float*)alloc(2 * DD * 8 * 4);
    ushort* wt     = (ushort*)alloc((size_t)2 * WTC * DD * 2);
    int*    deg    = (int*)alloc((size_t)N * 4);
    int*    locpre = (int*)alloc((size_t)N * 4);
    int*    bsumi  = (int*)alloc(64 * 4);
    int*    rowptr = (int*)alloc((size_t)(N + 1) * 4);
    int*    cursor = (int*)alloc((size_t)N * 4);
    int*    colidx = (int*)alloc((size_t)Etot * 4);

    // ---- CSR by destination + WA/Wt precompute (layer-invariant structure) ----
    hipMemsetAsync(deg, 0, (size_t)N * 4, stream);
    count_kernel<<<1024, 256, 0, stream>>>(ei, deg, E);
    scan1_kernel<<<NBLK, 256, 0, stream>>>(deg, locpre, bsumi, N);
    scan3_kernel<<<NBLK, 256, 0, stream>>>(locpre, bsumi, rowptr, cursor, N, NBLK);
    scatter_kernel<<<1024, 256, 0, stream>>>(ei, cursor, rowptr, colidx, E, Etot);
    wa_kernel<<<2 * DD, 64, 0, stream>>>(W, att_src, att_dst, wa);
    wt_kernel<<<2 * WTC, DD, 0, stream>>>(W, wa, wt);

    // ---- layer 1 ----
    gemm_mfma_kernel<0><<<(N + 63) / 64, 256, 0, stream>>>(
        x, nullptr, nullptr, nullptr, wt, hp, asrc, adst, N);
    agg_csr_kernel<<<NBAGG, 256, 0, stream>>>(
        rowptr, colidx, hp, asrc, adst, bias, y, pbuf, N);
    bnred_kernel<<<DD, 256, 0, stream>>>(pbuf, gamma, beta, scsh, NBAGG, N);

    // ---- layer 2 (layer-1 BN+ReLU+residual fused into gemm A-path; x1 -> xbuf) ----
    gemm_mfma_kernel<1><<<(N + 63) / 64, 256, 0, stream>>>(
        y, scsh, x, xbuf, wt + (size_t)WTC * DD, hp, asrc, adst, N);
    agg_csr_kernel<<<NBAGG, 256, 0, stream>>>(
        rowptr, colidx, hp, asrc, adst, bias + DD, y, pbuf, N);
    bnred_kernel<<<DD, 256, 0, stream>>>(pbuf, gamma + DD, beta + DD, scsh, NBAGG, N);
    bn_apply_kernel<<<2048, 256, 0, stream>>>(y, scsh, xbuf, out_final, N * DD / 4);
}

// Round 13
// 395.082 us; speedup vs baseline: 2.0534x; 1.0843x over previous
//
#include <hip/hip_runtime.h>

#define DD 96
#define HH 4
#define HD 384
#define NEG_SLOPE 0.2f
#define NB_STATS 128     // bnstats blocks
#define SCAN_BS 1024     // elements per scan block
#define WTC 400          // wt padded col count (384 W + 8 WA + 8 zero)

typedef unsigned int uint;
typedef unsigned short ushort;
typedef __attribute__((ext_vector_type(8))) short bf16x8;
typedef __attribute__((ext_vector_type(4))) float f32x4;

__device__ inline uint pack2bf(float lo, float hi) {   // round-to-nearest-even both halves
    uint ulo = __float_as_uint(lo); ulo += 0x7fffu + ((ulo >> 16) & 1u);
    uint uhi = __float_as_uint(hi); uhi += 0x7fffu + ((uhi >> 16) & 1u);
    return (ulo >> 16) | (uhi & 0xffff0000u);
}
__device__ inline ushort f2bf(float f) {
    uint u = __float_as_uint(f);
    u += 0x7fffu + ((u >> 16) & 1u);
    return (ushort)(u >> 16);
}

// ---------------- wt[l][c][k]: bf16 W^T (c<384); WA cols 384..391 computed inline ----
// WA[l][k][j] = sum over head-h(j) slice of W[l][k][:].att_{src,dst}[l][:], j=2h(+1).
__global__ void wt_kernel(const float* __restrict__ W, const float* __restrict__ att_src,
                          const float* __restrict__ att_dst, ushort* __restrict__ wt) {
    const int l = blockIdx.x / WTC;
    const int c = blockIdx.x % WTC;
    const int k = threadIdx.x;          // 0..95
    float v = 0.f;
    if (c < HD) {
        v = W[((size_t)l * DD + k) * HD + c];
    } else if (c < HD + 8) {
        const int j = c - HD, h = j >> 1;
        const float* Wr = W + ((size_t)l * DD + k) * HD + h * DD;
        const float* av = ((j & 1) == 0 ? att_src : att_dst) + (size_t)l * HD + h * DD;
        float s = 0.f;
#pragma unroll 4
        for (int i = 0; i < DD; i++) s = fmaf(Wr[i], av[i], s);
        v = s;
    }
    wt[((size_t)l * WTC + c) * DD + k] = f2bf(v);
}

// ---------------- MFMA GEMM + fused alpha (+ optional fused BN of previous layer) ----
template<int FUSE>
__global__ void __launch_bounds__(256) gemm_mfma_kernel(const float* __restrict__ xin,
        const float* __restrict__ scsh, const float* __restrict__ xres,
        float* __restrict__ xout,
        const ushort* __restrict__ wt, uint* __restrict__ hp,
        float* __restrict__ asrc, float* __restrict__ adst, int N) {
    const int t = threadIdx.x;
    const int w = t >> 6;
    const int lane = t & 63;
    const int q = lane & 15, g = lane >> 4;
    const int base = blockIdx.x * 64 + w * 16;
    const int nA = min(base + q, N - 1);          // A-row node (clamped for tail)

    f32x4 acc[25];
#pragma unroll
    for (int i = 0; i < 25; i++) acc[i] = (f32x4){0.f, 0.f, 0.f, 0.f};

#pragma unroll
    for (int s = 0; s < 3; s++) {
        const int kbase = s * 32 + g * 8;
        float xv[8];
        if (FUSE == 0) {
            const float* xp = xin + (size_t)nA * DD + kbase;
            const float4 xa = *(const float4*)xp;
            const float4 xb = *(const float4*)(xp + 4);
            xv[0]=xa.x; xv[1]=xa.y; xv[2]=xa.z; xv[3]=xa.w;
            xv[4]=xb.x; xv[5]=xb.y; xv[6]=xb.z; xv[7]=xb.w;
        } else {
            const float* yp = xin + (size_t)nA * DD + kbase;
            const float* rp = xres + (size_t)nA * DD + kbase;
            const float4 ya = *(const float4*)yp;
            const float4 yb = *(const float4*)(yp + 4);
            const float4 ra = *(const float4*)rp;
            const float4 rb = *(const float4*)(rp + 4);
            const float yv[8] = {ya.x,ya.y,ya.z,ya.w,yb.x,yb.y,yb.z,yb.w};
            const float rv[8] = {ra.x,ra.y,ra.z,ra.w,rb.x,rb.y,rb.z,rb.w};
#pragma unroll
            for (int j = 0; j < 8; j++) {
                const int d = kbase + j;
                float a = fmaf(yv[j], scsh[d], scsh[d + DD]);
                xv[j] = (a > 0.f ? a : 0.f) + rv[j];
            }
            float* op = xout + (size_t)nA * DD + kbase;
            *(float4*)op       = make_float4(xv[0], xv[1], xv[2], xv[3]);
            *(float4*)(op + 4) = make_float4(xv[4], xv[5], xv[6], xv[7]);
        }
        union { uint u[4]; bf16x8 v; } A;
        A.u[0] = pack2bf(xv[0], xv[1]);
        A.u[1] = pack2bf(xv[2], xv[3]);
        A.u[2] = pack2bf(xv[4], xv[5]);
        A.u[3] = pack2bf(xv[6], xv[7]);
#pragma unroll
        for (int tt = 0; tt < 25; tt++) {
            const ushort* wp = wt + (size_t)(tt * 16 + q) * DD + kbase;
            union { uint4 u4; bf16x8 v; } B;
            B.u4 = *(const uint4*)wp;
            acc[tt] = __builtin_amdgcn_mfma_f32_16x16x32_bf16(A.v, B.v, acc[tt], 0, 0, 0);
        }
    }
#pragma unroll
    for (int r = 0; r < 4; r++) {
        const int node = base + g * 4 + r;
        if (node < N) {
            uint* hr = hp + (size_t)node * 192;
#pragma unroll
            for (int p = 0; p < 3; p++)
#pragma unroll
                for (int tt = 0; tt < 4; tt++)
                    hr[p * 64 + tt * 16 + q] = pack2bf(acc[p * 8 + tt][r], acc[p * 8 + tt + 4][r]);
            if (q < 8) {
                const float v = acc[24][r];
                if ((q & 1) == 0) asrc[node * 4 + (q >> 1)] = v;
                else              adst[node * 4 + (q >> 1)] = v;
            }
        }
    }
}

// ---------------- CSR build ----------------
__global__ void count_kernel(const int* __restrict__ ei, int* __restrict__ deg, int E) {
    int i = blockIdx.x * blockDim.x + threadIdx.x;
    const int stride = gridDim.x * blockDim.x;
    for (; i < E; i += stride) atomicAdd(&deg[ei[E + i]], 1);
}

__global__ void scan1_kernel(const int* __restrict__ deg, int* __restrict__ locpre,
                             int* __restrict__ bsum, int N) {
    __shared__ int ts[256];
    const int t = threadIdx.x;
    const int base = blockIdx.x * SCAN_BS + t * 4;
    int e0 = 0, e1 = 0, e2 = 0, e3 = 0;
    if (base + 3 < N) {
        const int4 v = *(const int4*)(deg + base);
        e0 = v.x + 1; e1 = v.y + 1; e2 = v.z + 1; e3 = v.w + 1;
    } else {
        if (base     < N) e0 = deg[base]     + 1;
        if (base + 1 < N) e1 = deg[base + 1] + 1;
        if (base + 2 < N) e2 = deg[base + 2] + 1;
        if (base + 3 < N) e3 = deg[base + 3] + 1;
    }
    const int s = e0 + e1 + e2 + e3;
    ts[t] = s;
    __syncthreads();
    for (int off = 1; off < 256; off <<= 1) {
        const int u = (t >= off) ? ts[t - off] : 0;
        __syncthreads();
        ts[t] += u;
        __syncthreads();
    }
    const int ex = ts[t] - s;
    if (base + 3 < N) {
        *(int4*)(locpre + base) = make_int4(ex, ex + e0, ex + e0 + e1, ex + e0 + e1 + e2);
    } else if (base < N) {
        locpre[base] = ex;
        if (base + 1 < N) locpre[base + 1] = ex + e0;
        if (base + 2 < N) locpre[base + 2] = ex + e0 + e1;
    }
    if (t == 255) bsum[blockIdx.x] = ts[255];
}

// phase 2+3 merged: each block redundantly scans the (<=64) block totals
__global__ void scan3_kernel(const int* __restrict__ locpre, const int* __restrict__ bsum,
                             int* __restrict__ rowptr, int* __restrict__ cursor,
                             int N, int NBLK) {
    __shared__ int s_boff, s_total;
    const int t = threadIdx.x;
    if (t < 64) {
        const int mine = (t < NBLK) ? bsum[t] : 0;
        int incl = mine;
#pragma unroll
        for (int off = 1; off < 64; off <<= 1) {
            const int u = __shfl_up(incl, off);
            if (t >= off) incl += u;
        }
        if (t == (int)blockIdx.x) s_boff = incl - mine;
        if (t == NBLK - 1) s_total = incl;
    }
    __syncthreads();
    const int boff = s_boff;
    const int base = blockIdx.x * SCAN_BS + t * 4;
    if (base + 3 < N) {
        int4 v = *(const int4*)(locpre + base);
        v.x += boff; v.y += boff; v.z += boff; v.w += boff;
        *(int4*)(rowptr + base) = v;
        *(int4*)(cursor + base) = v;
    } else {
        for (int i = base; i < N && i < base + 4; i++) {
            const int r = locpre[i] + boff;
            rowptr[i] = r; cursor[i] = r;
        }
    }
    if (blockIdx.x == 0 && t == 0) rowptr[N] = s_total;
}

__global__ void scatter_kernel(const int* __restrict__ ei, int* __restrict__ cursor,
                               const int* __restrict__ rowptr, int* __restrict__ col,
                               int E, int Etot) {
    int i = blockIdx.x * blockDim.x + threadIdx.x;
    const int stride = gridDim.x * blockDim.x;
    for (; i < Etot; i += stride) {
        if (i < E) {
            const int src = ei[i], dst = ei[E + i];
            col[atomicAdd(&cursor[dst], 1)] = src;
        } else {
            const int n = i - E;
            col[rowptr[n + 1] - 1] = n;     // self-loop slot, non-atomic
        }
    }
}

// ---------------- fused aggregate: inline edge weights (lane-parallel) + gather -----
#define EDGE_FMA(u0, u1, u2, w4)                                                      \
    { den0 += w4.x; den1 += w4.y; den2 += w4.z; den3 += w4.w;                         \
      const float cf1 = hi32 ? w4.y : w4.x;                                           \
      const float cf4 = hi32 ? w4.w : w4.z;                                           \
      acc0 = fmaf(__uint_as_float(u0 << 16), w4.x, acc0);                             \
      acc1 = fmaf(__uint_as_float(u0 & 0xffff0000u), cf1, acc1);                      \
      acc2 = fmaf(__uint_as_float(u1 << 16), w4.y, acc2);                             \
      acc3 = fmaf(__uint_as_float(u1 & 0xffff0000u), w4.z, acc3);                     \
      acc4 = fmaf(__uint_as_float(u2 << 16), cf4, acc4);                              \
      acc5 = fmaf(__uint_as_float(u2 & 0xffff0000u), w4.w, acc5); }

__global__ void __launch_bounds__(256) agg_csr_kernel(
        const int* __restrict__ rowptr, const int* __restrict__ col,
        const uint* __restrict__ hp, const float* __restrict__ asrc,
        const float* __restrict__ adst, const float* __restrict__ bias,
        float* __restrict__ y, int N) {
    __shared__ float4 wls[4][64];
    __shared__ int    sls[4][64];
    const int t = threadIdx.x;
    const int lane = t & 63;
    const int wv = t >> 6;
    const bool hi32 = lane >= 32;
    const int n = (blockIdx.x * blockDim.x + t) >> 6;
    if (n >= N) return;
    const int beg = rowptr[n], endp = rowptr[n + 1];
    const float4 adv = ((const float4*)adst)[n];
    float acc0=0,acc1=0,acc2=0,acc3=0,acc4=0,acc5=0;
    float den0=0,den1=0,den2=0,den3=0;

    for (int cs = beg; cs < endp; cs += 64) {
        const int cnt = min(64, endp - cs);
        if (lane < cnt) {
            const int s = col[cs + lane];
            const float4 av = ((const float4*)asrc)[s];
            float e0 = av.x + adv.x, e1 = av.y + adv.y;
            float e2 = av.z + adv.z, e3 = av.w + adv.w;
            e0 = e0 > 0.f ? e0 : NEG_SLOPE * e0;
            e1 = e1 > 0.f ? e1 : NEG_SLOPE * e1;
            e2 = e2 > 0.f ? e2 : NEG_SLOPE * e2;
            e3 = e3 > 0.f ? e3 : NEG_SLOPE * e3;
            sls[wv][lane] = s;
            wls[wv][lane] = make_float4(__expf(e0), __expf(e1), __expf(e2), __expf(e3));
        }
        __builtin_amdgcn_wave_barrier();    // wave-local LDS: per-wave DS pipe is in-order
        int j = 0;
        for (; j + 4 <= cnt; j += 4) {
            const int4 sv = *(const int4*)&sls[wv][j];
            const float4 wA = wls[wv][j],     wB = wls[wv][j + 1];
            const float4 wC = wls[wv][j + 2], wD = wls[wv][j + 3];
            const uint* h0 = hp + (size_t)sv.x * 192 + lane;
            const uint* h1 = hp + (size_t)sv.y * 192 + lane;
            const uint* h2 = hp + (size_t)sv.z * 192 + lane;
            const uint* h3 = hp + (size_t)sv.w * 192 + lane;
            const uint u00 = h0[0], u01 = h0[64], u02 = h0[128];
            const uint u10 = h1[0], u11 = h1[64], u12 = h1[128];
            const uint u20 = h2[0], u21 = h2[64], u22 = h2[128];
            const uint u30 = h3[0], u31 = h3[64], u32 = h3[128];
            EDGE_FMA(u00, u01, u02, wA);
            EDGE_FMA(u10, u11, u12, wB);
            EDGE_FMA(u20, u21, u22, wC);
            EDGE_FMA(u30, u31, u32, wD);
        }
        for (; j < cnt; j++) {
            const int s0 = sls[wv][j];
            const float4 wA = wls[wv][j];
            const uint* h0 = hp + (size_t)s0 * 192 + lane;
            const uint u00 = h0[0], u01 = h0[64], u02 = h0[128];
            EDGE_FMA(u00, u01, u02, wA);
        }
        __builtin_amdgcn_wave_barrier();
    }
    const float r0 = 0.25f / (den0 + 1e-16f);
    const float r1 = 0.25f / (den1 + 1e-16f);
    const float r2 = 0.25f / (den2 + 1e-16f);
    const float r3 = 0.25f / (den3 + 1e-16f);
    const float rc1 = hi32 ? r1 : r0;
    const float rc4 = hi32 ? r3 : r2;
    const float A = acc0 * r0 + acc3 * r2;
    const float B = acc1 * rc1 + acc4 * rc4;
    const float C = acc2 * r1 + acc5 * r3;
    const float shB = __shfl_xor(B, 32);
    const float shC = __shfl_xor(C, 32);
    float* yr = y + (size_t)n * DD;
    yr[lane] = A + (hi32 ? shC : shB) + bias[lane];
    if (!hi32) yr[64 + lane] = B + shC + bias[64 + lane];
}

// ---------------- BN stats: deterministic block partials ----------------
__global__ void bnstats_kernel(const float* __restrict__ y, float* __restrict__ pbuf,
                               int total4) {
    __shared__ float ps[384 * 4];
    __shared__ float qs[384 * 4];
    const int t = threadIdx.x;          // 0..383
    const int stride = gridDim.x * 384;
    float s0=0,s1=0,s2=0,s3=0,q0=0,q1=0,q2=0,q3=0;
    for (int i = blockIdx.x * 384 + t; i < total4; i += stride) {
        const float4 v = ((const float4*)y)[i];
        s0 += v.x; q0 = fmaf(v.x, v.x, q0);
        s1 += v.y; q1 = fmaf(v.y, v.y, q1);
        s2 += v.z; q2 = fmaf(v.z, v.z, q2);
        s3 += v.w; q3 = fmaf(v.w, v.w, q3);
    }
    ps[t*4+0]=s0; ps[t*4+1]=s1; ps[t*4+2]=s2; ps[t*4+3]=s3;
    qs[t*4+0]=q0; qs[t*4+1]=q1; qs[t*4+2]=q2; qs[t*4+3]=q3;
    __syncthreads();
    if (t < 192) {
        const int d = t % 96;
        const float* src = (t < 96) ? ps : qs;
        float r = 0.f;
#pragma unroll
        for (int m = 0; m < 16; m++) r += src[d + 96 * m];
        pbuf[blockIdx.x * 192 + t] = r;
    }
}

__global__ void bnfin_kernel(const float* __restrict__ pbuf, const float* __restrict__ gamma,
                             const float* __restrict__ beta, float* __restrict__ scsh, int N) {
    const int d = threadIdx.x;   // 96
    float s = 0.f, q = 0.f;
    for (int b = 0; b < NB_STATS; b++) {
        s += pbuf[b * 192 + d];
        q += pbuf[b * 192 + 96 + d];
    }
    const float invN = 1.f / (float)N;
    const float mu = s * invN;
    const float var = q * invN - mu * mu;
    const float sc = gamma[d] * rsqrtf(var + 1e-5f);
    scsh[d] = sc;
    scsh[d + DD] = beta[d] - mu * sc;
}

__global__ void bn_apply_kernel(const float* __restrict__ y, const float* __restrict__ scsh,
                                const float* __restrict__ xin, float* __restrict__ xout,
                                int total4) {
    int i = blockIdx.x * blockDim.x + threadIdx.x;
    const int stride = gridDim.x * blockDim.x;
    for (; i < total4; i += stride) {
        const int d4 = (i % 24) * 4;
        const float4 v = ((const float4*)y)[i];
        const float4 xi = ((const float4*)xin)[i];
        float4 o; float a;
        a = fmaf(v.x, scsh[d4],     scsh[d4 + DD]);     o.x = (a > 0.f ? a : 0.f) + xi.x;
        a = fmaf(v.y, scsh[d4 + 1], scsh[d4 + 1 + DD]); o.y = (a > 0.f ? a : 0.f) + xi.y;
        a = fmaf(v.z, scsh[d4 + 2], scsh[d4 + 2 + DD]); o.z = (a > 0.f ? a : 0.f) + xi.z;
        a = fmaf(v.w, scsh[d4 + 3], scsh[d4 + 3 + DD]); o.w = (a > 0.f ? a : 0.f) + xi.w;
        ((float4*)xout)[i] = o;
    }
}

extern "C" void kernel_launch(void* const* d_in, const int* in_sizes, int n_in,
                              void* d_out, int out_size, void* d_ws, size_t ws_size,
                              hipStream_t stream) {
    const float* x        = (const float*)d_in[0];
    const int*   ei       = (const int*)d_in[1];
    const float* W        = (const float*)d_in[2];
    const float* att_src  = (const float*)d_in[3];
    const float* att_dst  = (const float*)d_in[4];
    const float* bias     = (const float*)d_in[5];
    const float* gamma    = (const float*)d_in[6];
    const float* beta     = (const float*)d_in[7];
    float* out_final = (float*)d_out;

    const int N = in_sizes[0] / DD;     // 50000
    const int E = in_sizes[1] / 2;      // 800000
    const int Etot = E + N;
    const int NBLK = (N + SCAN_BS - 1) / SCAN_BS;   // 49 (must be <= 64)

    char* ws = (char*)d_ws;
    size_t off = 0;
    auto alloc = [&](size_t bytes) -> void* {
        void* p = ws + off;
        off += (bytes + 255) & ~(size_t)255;
        return p;
    };
    uint*   hp     = (uint*)alloc((size_t)N * 192 * 4);
    float*  asrc   = (float*)alloc((size_t)N * HH * 4);
    float*  adst   = (float*)alloc((size_t)N * HH * 4);
    float*  y      = (float*)alloc((size_t)N * DD * 4);
    float*  xbuf   = (float*)alloc((size_t)N * DD * 4);
    float*  pbuf   = (float*)alloc((size_t)NB_STATS * 192 * 4);
    float*  scsh   = (float*)alloc(2 * DD * 4);
    ushort* wt     = (ushort*)alloc((size_t)2 * WTC * DD * 2);
    int*    deg    = (int*)alloc((size_t)N * 4);
    int*    locpre = (int*)alloc((size_t)N * 4);
    int*    bsumi  = (int*)alloc(64 * 4);
    int*    rowptr = (int*)alloc((size_t)(N + 1) * 4);
    int*    cursor = (int*)alloc((size_t)N * 4);
    int*    colidx = (int*)alloc((size_t)Etot * 4);

    // ---- CSR by destination + Wt(+WA) precompute (layer-invariant structure) ----
    hipMemsetAsync(deg, 0, (size_t)N * 4, stream);
    count_kernel<<<1024, 256, 0, stream>>>(ei, deg, E);
    scan1_kernel<<<NBLK, 256, 0, stream>>>(deg, locpre, bsumi, N);
    scan3_kernel<<<NBLK, 256, 0, stream>>>(locpre, bsumi, rowptr, cursor, N, NBLK);
    scatter_kernel<<<1024, 256, 0, stream>>>(ei, cursor, rowptr, colidx, E, Etot);
    wt_kernel<<<2 * WTC, DD, 0, stream>>>(W, att_src, att_dst, wt);

    // ---- layer 1 ----
    gemm_mfma_kernel<0><<<(N + 63) / 64, 256, 0, stream>>>(
        x, nullptr, nullptr, nullptr, wt, hp, asrc, adst, N);
    agg_csr_kernel<<<(N * 64 + 255) / 256, 256, 0, stream>>>(
        rowptr, colidx, hp, asrc, adst, bias, y, N);
    bnstats_kernel<<<NB_STATS, 384, 0, stream>>>(y, pbuf, N * DD / 4);
    bnfin_kernel<<<1, DD, 0, stream>>>(pbuf, gamma, beta, scsh, N);

    // ---- layer 2 (layer-1 BN+ReLU+residual fused into gemm A-path; x1 -> xbuf) ----
    gemm_mfma_kernel<1><<<(N + 63) / 64, 256, 0, stream>>>(
        y, scsh, x, xbuf, wt + (size_t)WTC * DD, hp, asrc, adst, N);
    agg_csr_kernel<<<(N * 64 + 255) / 256, 256, 0, stream>>>(
        rowptr, colidx, hp, asrc, adst, bias + DD, y, N);
    bnstats_kernel<<<NB_STATS, 384, 0, stream>>>(y, pbuf, N * DD / 4);
    bnfin_kernel<<<1, DD, 0, stream>>>(pbuf, gamma + DD, beta + DD, scsh, N);
    bn_apply_kernel<<<2048, 256, 0, stream>>>(y, scsh, xbuf, out_final, N * DD / 4);
}